// Round 2
// baseline (208.652 us; speedup 1.0000x reference)
//
#include <hip/hip_runtime.h>
#include <hip/hip_bf16.h>

// B=16, N=4096, C=256, WS=8 -> 1024 windows x 64 tokens; NH=8, HD=32, LK=32, G=16.
// fp32 in/out. MFMA 16x16x32 bf16.
// R6: all LDS tiles use power-of-2 row strides + XOR 16B-chunk swizzle
//   (T2) -> conflict-free ds_read_b128 in all phases (was 4-8-way on every
//   padded-stride tile). bf16 converts via HW v_cvt_pk_bf16_f32. Prep grid
//   widened 130->258 blocks. LDS 148->128 KB. Structure/barriers unchanged.
// R6b: bit-extraction via memcpy (__hip_bfloat16x2 is not trivially copyable,
//   __builtin_bit_cast rejected by hipcc).

typedef unsigned int uint;
typedef __attribute__((ext_vector_type(8))) short short8;   // 8 x bf16
typedef __attribute__((ext_vector_type(4))) float f32x4;

__device__ __forceinline__ float bup(uint hs) {
    return __uint_as_float(hs << 16);
}
__device__ __forceinline__ uint f2b(float f) {   // fp32 -> bf16 bits (RNE, HW cvt)
    __hip_bfloat16 h = __float2bfloat16(f);
    unsigned short u;
    __builtin_memcpy(&u, &h, 2);
    return (uint)u;
}
__device__ __forceinline__ uint f2b2(float a, float b) {  // pack 2 (v_cvt_pk_bf16_f32)
    __hip_bfloat162 h = __float22bfloat162_rn(make_float2(a, b));
    uint u;
    __builtin_memcpy(&u, &h, 4);
    return u;
}
__device__ __forceinline__ f32x4 mfma16(short8 a, short8 b, f32x4 c) {
    return __builtin_amdgcn_mfma_f32_16x16x32_bf16(a, b, c, 0, 0, 0);
}
// XOR-swizzled LDS indices (16-B chunks within a row; units = shorts).
// Writes and reads use the same involution, so logical indexing is unchanged.
__device__ __forceinline__ int sw256(int r, int c) { return r * 256 + (c ^ ((r & 7) << 3)); }
__device__ __forceinline__ int sw64 (int r, int c) { return r * 64  + (c ^ ((r & 7) << 3)); }
__device__ __forceinline__ int sw32 (int r, int c) { return r * 32  + (c ^ ((r & 3) << 3)); }

// ---- workspace layout (shorts) ----
#define WS_WHQ 0          // [48 tn][8 tk][64 lane][8]  = 196608 (hi only)
#define WS_WHP 196608     // [16 tn][8 tk][64 lane][8]  = 65536
#define WS_WLP 262144     // 65536
#define WS_EKT 327680     // [2 tm][2 tk][64 lane][8]   = 2048
#define WS_EVT 329728     // total 331776 shorts = 663552 B

__global__ void __launch_bounds__(256)
eswa_prep(const float* __restrict__ Wqkv, const float* __restrict__ Wproj,
          const float* __restrict__ Ek, const float* __restrict__ Ev,
          short* __restrict__ wsp)
{
    const int blk = blockIdx.x, thr = threadIdx.x;
    if (blk < 192) {                      // Wqkv hi: 48 tn x 8 tk x 64 lane, j-half
        const int jh = blk & 1;
        const int g = (blk >> 1) * 256 + thr;
        const int lane = g & 63, tk = (g >> 6) & 7, tn = g >> 9;
        const int quad = lane >> 4, l16 = lane & 15;
        const int c = tn * 16 + l16;
        const int r0 = tk * 32 + quad * 8 + jh * 4;
        const float w0 = Wqkv[(r0 + 0) * 768 + c], w1 = Wqkv[(r0 + 1) * 768 + c];
        const float w2 = Wqkv[(r0 + 2) * 768 + c], w3 = Wqkv[(r0 + 3) * 768 + c];
        *(uint2*)(wsp + WS_WHQ + ((tn * 8 + tk) * 64 + lane) * 8 + jh * 4) =
            make_uint2(f2b2(w0, w1), f2b2(w2, w3));
    } else if (blk < 256) {               // Wproj hi+lo: 16 tn x 8 tk x 64 lane, j-half
        const int idx = blk - 192, jh = idx & 1;
        const int g = (idx >> 1) * 256 + thr;
        const int lane = g & 63, tk = (g >> 6) & 7, tn = g >> 9;
        const int quad = lane >> 4, l16 = lane & 15;
        const int c = tn * 16 + l16;
        const int r0 = tk * 32 + quad * 8 + jh * 4;
        float w[4];
        #pragma unroll
        for (int j = 0; j < 4; ++j) w[j] = Wproj[(r0 + j) * 256 + c];
        const uint h01 = f2b2(w[0], w[1]), h23 = f2b2(w[2], w[3]);
        const float l0 = w[0] - bup(h01 & 0xffffu), l1 = w[1] - bup(h01 >> 16);
        const float l2 = w[2] - bup(h23 & 0xffffu), l3 = w[3] - bup(h23 >> 16);
        const int o = ((tn * 8 + tk) * 64 + lane) * 8 + jh * 4;
        *(uint2*)(wsp + WS_WHP + o) = make_uint2(h01, h23);
        *(uint2*)(wsp + WS_WLP + o) = make_uint2(f2b2(l0, l1), f2b2(l2, l3));
    } else {                              // Ek (blk 256) / Ev (blk 257)
        const float* E = (blk == 256) ? Ek : Ev;
        const int base = (blk == 256) ? WS_EKT : WS_EVT;
        const int lane = thr & 63, tk = (thr >> 6) & 1, tm = (thr >> 7) & 1;
        const int quad = lane >> 4, l16 = lane & 15;
        const int lk = tm * 16 + l16;
        uint pk[4];
        #pragma unroll
        for (int jp = 0; jp < 4; ++jp) {
            const int t = tk * 32 + quad * 8 + jp * 2;
            pk[jp] = f2b2(E[t * 32 + lk], E[(t + 1) * 32 + lk]);
        }
        *(uint4*)(wsp + base + ((tm * 2 + tk) * 64 + lane) * 8) =
            make_uint4(pk[0], pk[1], pk[2], pk[3]);
    }
}

// ---- LDS layout (bytes), total 131072 ----
// xh   bf16 [64][256] sw256 @ 0      32768  (dead after QKV; attn [64][256]
//                                            sw256 overlays it after B5)
// arena[h] @ 32768 + h*12288, per head 12288:
//   q  [64][32] sw32 @ +0    (4096) -> P(s=0) [32][64] sw64 after B5
//   kT [32][64] sw64 @ +4096 (4096) -> kfull [48][32] sw32 -> P(s=1) after B5
//   vT [32][64] sw64 @ +8192 (4096) -> vfullT [32][64] sw64 in place
#define SMEM_BYTES 131072

__global__ void __launch_bounds__(1024, 4)
eswa_main(const float* __restrict__ x, const float* __restrict__ bqkv,
          const float* __restrict__ kbank, const float* __restrict__ vbank,
          const float* __restrict__ bproj, const short* __restrict__ wsp,
          float* __restrict__ out)
{
    extern __shared__ char smem[];
    short* xh = (short*)smem;                     // [64][256] sw256

    const int tid  = threadIdx.x;
    const int wave = tid >> 6;                    // 0..15
    const int lane = tid & 63;
    const int quad = lane >> 4;
    const int l16  = lane & 15;

    const int b  = blockIdx.x >> 6;
    const int w  = blockIdx.x & 63;
    const int rw = w >> 3;
    const int cw = w & 7;

    // ================= stage: x -> bf16 LDS [token][256] swizzled ==========
    #pragma unroll
    for (int i = 0; i < 4; ++i) {
        const int vi = tid + 1024 * i;            // 0..4095
        const int t  = vi >> 6;
        const int c  = (vi & 63) * 4;
        const int n  = (rw * 8 + (t >> 3)) * 64 + cw * 8 + (t & 7);
        const float4 xv = *(const float4*)(x + (size_t)(b * 4096 + n) * 256 + c);
        *(uint2*)(xh + sw256(t, c)) = make_uint2(f2b2(xv.x, xv.y), f2b2(xv.z, xv.w));
    }
    __syncthreads();   // B1

    // ================= phase 1: QKV all heads (W-hi only) =================
    // wave w owns n-tiles w*3 .. w*3+2, all 4 m-tiles.
    {
        const short* Whq = wsp + WS_WHQ;
        const int tn0 = wave * 3;
        f32x4 acc[3][4];
        #pragma unroll
        for (int p = 0; p < 3; ++p) {
            const int tn = tn0 + p;
            const int sec = tn >> 4, hh = (tn >> 1) & 7, half = tn & 1;
            const float bv = bqkv[sec * 256 + hh * 32 + half * 16 + l16];
            #pragma unroll
            for (int m = 0; m < 4; ++m) acc[p][m] = (f32x4){bv, bv, bv, bv};
        }
        #pragma unroll 2
        for (int tk = 0; tk < 8; ++tk) {
            short8 af[4];
            #pragma unroll
            for (int m = 0; m < 4; ++m)
                af[m] = *(const short8*)(xh + sw256(m * 16 + l16, tk * 32 + quad * 8));
            #pragma unroll
            for (int p = 0; p < 3; ++p) {
                const short8 bh = *(const short8*)(Whq + (((tn0 + p) * 8 + tk) * 64 + lane) * 8);
                #pragma unroll
                for (int m = 0; m < 4; ++m)
                    acc[p][m] = mfma16(af[m], bh, acc[p][m]);
            }
        }
        // epilogue: scatter to per-head arenas (q pre-scaled by 1/sqrt(hd))
        #pragma unroll
        for (int p = 0; p < 3; ++p) {
            const int tn = tn0 + p;
            const int sec = tn >> 4, hh = (tn >> 1) & 7, half = tn & 1;
            short* arena = (short*)(smem + 32768 + hh * 12288);
            #pragma unroll
            for (int m = 0; m < 4; ++m) {
                #pragma unroll
                for (int r = 0; r < 4; ++r) {
                    const int t = m * 16 + quad * 4 + r;
                    const float v = acc[p][m][r];
                    if (sec == 0)
                        arena[sw32(t, half * 16 + l16)] =
                            (short)f2b(v * 0.17677669529663687f);
                    else if (sec == 1)
                        (arena + 2048)[sw64(half * 16 + l16, t)] = (short)f2b(v);
                    else
                        (arena + 4096)[sw64(half * 16 + l16, t)] = (short)f2b(v);
                }
            }
        }
    }
    __syncthreads();   // B2

    // ====== phase 2: head h = wave>>1, half s = wave&1 ======
    const int h = wave >> 1, s = wave & 1;
    short* arena = (short*)(smem + 32768 + h * 12288);
    short* qsp = arena;            // q [64][32] sw32 -> P(s=0) [32][64] sw64
    short* kTp = arena + 2048;     // kT [32][64] sw64 -> kfull [48][32] sw32 -> P(s=1)
    short* vTp = arena + 4096;     // vT/vfullT [32][64] sw64
    const int gB  = s * 8 + (lane >> 3);     // bank row 0..15
    const int dqB = (lane & 7) * 4;          // bank d-offset

    // --- 2a-load: raw k/v B-frags + E-frags + bank values (before overwrite) ---
    short8 kB[2][2], vB[2][2];
    #pragma unroll
    for (int tn = 0; tn < 2; ++tn)
        #pragma unroll
        for (int tk = 0; tk < 2; ++tk) {
            kB[tn][tk] = *(const short8*)(kTp + sw64(tn * 16 + l16, tk * 32 + quad * 8));
            vB[tn][tk] = *(const short8*)(vTp + sw64(tn * 16 + l16, tk * 32 + quad * 8));
        }
    short8 akE[2], avE[2];
    #pragma unroll
    for (int tk = 0; tk < 2; ++tk) {
        akE[tk] = *(const short8*)(wsp + WS_EKT + ((s * 2 + tk) * 64 + lane) * 8);
        avE[tk] = *(const short8*)(wsp + WS_EVT + ((s * 2 + tk) * 64 + lane) * 8);
    }
    const float4 kbv = *(const float4*)(kbank + gB * 256 + h * 32 + dqB);
    const float4 vbv = *(const float4*)(vbank + gB * 256 + h * 32 + dqB);
    __syncthreads();   // B3: all raw-frag loads done before overwrites

    // --- 2a-compute: compression (this wave: tm = s) + bank fill + pads ---
    {
        f32x4 kc[2], vc[2];
        #pragma unroll
        for (int tn = 0; tn < 2; ++tn) { kc[tn] = (f32x4){0,0,0,0}; vc[tn] = (f32x4){0,0,0,0}; }
        #pragma unroll
        for (int tk = 0; tk < 2; ++tk)
            #pragma unroll
            for (int tn = 0; tn < 2; ++tn) {
                kc[tn] = mfma16(akE[tk], kB[tn][tk], kc[tn]);
                vc[tn] = mfma16(avE[tk], vB[tn][tk], vc[tn]);
            }
        #pragma unroll
        for (int tn = 0; tn < 2; ++tn)
            #pragma unroll
            for (int r = 0; r < 4; ++r) {
                const int lk = s * 16 + quad * 4 + r;
                const int d  = tn * 16 + l16;
                kTp[sw32(lk, d)] = (short)f2b(kc[tn][r]);
                vTp[sw64(d, lk)] = (short)f2b(vc[tn][r]);
            }
        // bank rows 32..47
        *(uint2*)(kTp + sw32(32 + gB, dqB)) =
            make_uint2(f2b2(kbv.x, kbv.y), f2b2(kbv.z, kbv.w));
        vTp[sw64(dqB + 0, 32 + gB)] = (short)f2b(vbv.x);
        vTp[sw64(dqB + 1, 32 + gB)] = (short)f2b(vbv.y);
        vTp[sw64(dqB + 2, 32 + gB)] = (short)f2b(vbv.z);
        vTp[sw64(dqB + 3, 32 + gB)] = (short)f2b(vbv.w);
        // zero vfullT key-cols 48..63 (PV K-pad), one wave of the pair
        if (s == 0)
            *(uint4*)(vTp + sw64(lane >> 1, 48 + (lane & 1) * 8)) = make_uint4(0, 0, 0, 0);
    }
    __syncthreads();   // B4: kfull/vfullT complete

    // --- 2b: scores for m-tiles {2s, 2s+1} (q pre-scaled) ---
    f32x4 sc[2][3];
    f32x4 inv4[2];
    {
        short8 qA[2], kfB[3];
        #pragma unroll
        for (int ml = 0; ml < 2; ++ml)
            qA[ml] = *(const short8*)(qsp + sw32((2 * s + ml) * 16 + l16, quad * 8));
        #pragma unroll
        for (int n = 0; n < 3; ++n)
            kfB[n] = *(const short8*)(kTp + sw32(n * 16 + l16, quad * 8));
        #pragma unroll
        for (int ml = 0; ml < 2; ++ml)
            #pragma unroll
            for (int n = 0; n < 3; ++n) {
                sc[ml][n] = (f32x4){0, 0, 0, 0};
                sc[ml][n] = mfma16(qA[ml], kfB[n], sc[ml][n]);
            }
        // --- 2c: softmax in registers (reduce across l16 via shfl) ---
        #pragma unroll
        for (int ml = 0; ml < 2; ++ml) {
            #pragma unroll
            for (int r = 0; r < 4; ++r) {
                float mm = fmaxf(fmaxf(sc[ml][0][r], sc[ml][1][r]), sc[ml][2][r]);
                mm = fmaxf(mm, __shfl_xor(mm, 1));
                mm = fmaxf(mm, __shfl_xor(mm, 2));
                mm = fmaxf(mm, __shfl_xor(mm, 4));
                mm = fmaxf(mm, __shfl_xor(mm, 8));
                const float e0 = __expf(sc[ml][0][r] - mm);
                const float e1 = __expf(sc[ml][1][r] - mm);
                const float e2 = __expf(sc[ml][2][r] - mm);
                sc[ml][0][r] = e0; sc[ml][1][r] = e1; sc[ml][2][r] = e2;
                float su = e0 + e1 + e2;
                su += __shfl_xor(su, 1);
                su += __shfl_xor(su, 2);
                su += __shfl_xor(su, 4);
                su += __shfl_xor(su, 8);
                inv4[ml][r] = 1.0f / su;
            }
        }
    }
    __syncthreads();   // B5: q/kfull dead, safe to overwrite with P

    // --- 2d: PV for this wave's 32 tokens ---
    {
        short* Pb = (s == 0) ? qsp : kTp;      // [32][64] sw64
        #pragma unroll
        for (int ml = 0; ml < 2; ++ml)
            #pragma unroll
            for (int n = 0; n < 3; ++n)
                #pragma unroll
                for (int r = 0; r < 4; ++r)
                    Pb[sw64(ml * 16 + quad * 4 + r, n * 16 + l16)] =
                        (short)f2b(sc[ml][n][r] * inv4[ml][r]);
        *(uint4*)(Pb + sw64(lane >> 1, 48 + (lane & 1) * 8)) = make_uint4(0, 0, 0, 0);

        short8 vfB[2][2], pA[2][2];
        #pragma unroll
        for (int tn = 0; tn < 2; ++tn)
            #pragma unroll
            for (int tk = 0; tk < 2; ++tk)
                vfB[tn][tk] = *(const short8*)(vTp + sw64(tn * 16 + l16, tk * 32 + quad * 8));
        #pragma unroll
        for (int ml = 0; ml < 2; ++ml)
            #pragma unroll
            for (int tk = 0; tk < 2; ++tk)
                pA[ml][tk] = *(const short8*)(Pb + sw64(ml * 16 + l16, tk * 32 + quad * 8));
        #pragma unroll
        for (int ml = 0; ml < 2; ++ml)
            #pragma unroll
            for (int tn = 0; tn < 2; ++tn) {
                f32x4 oa = (f32x4){0, 0, 0, 0};
                oa = mfma16(pA[ml][0], vfB[tn][0], oa);
                oa = mfma16(pA[ml][1], vfB[tn][1], oa);
                #pragma unroll
                for (int r = 0; r < 4; ++r) {
                    const int t = s * 32 + ml * 16 + quad * 4 + r;
                    ((short*)smem)[sw256(t, h * 32 + tn * 16 + l16)] =
                        (short)f2b(oa[r]);
                }
            }
    }
    __syncthreads();   // B6

    // ================= phase 3: output projection =================
    // wave w: n-tile w, all 4 m-tiles; W hi+lo.
    {
        const short* Whp = wsp + WS_WHP;
        const short* Wlp = wsp + WS_WLP;
        const short* attnS = (const short*)smem;   // [64][256] sw256
        const int tn = wave;
        f32x4 acc[4];
        {
            const float bi = bproj[tn * 16 + l16];
            #pragma unroll
            for (int m = 0; m < 4; ++m) acc[m] = (f32x4){bi, bi, bi, bi};
        }
        #pragma unroll 2
        for (int tk = 0; tk < 8; ++tk) {
            short8 aA[4];
            #pragma unroll
            for (int m = 0; m < 4; ++m)
                aA[m] = *(const short8*)(attnS + sw256(m * 16 + l16, tk * 32 + quad * 8));
            const int bo = ((tn * 8 + tk) * 64 + lane) * 8;
            const short8 bh = *(const short8*)(Whp + bo);
            const short8 bl = *(const short8*)(Wlp + bo);
            #pragma unroll
            for (int m = 0; m < 4; ++m) {
                acc[m] = mfma16(aA[m], bh, acc[m]);
                acc[m] = mfma16(aA[m], bl, acc[m]);
            }
        }
        #pragma unroll
        for (int m = 0; m < 4; ++m)
            #pragma unroll
            for (int r = 0; r < 4; ++r) {
                const int t = m * 16 + quad * 4 + r;
                const int n = (rw * 8 + (t >> 3)) * 64 + cw * 8 + (t & 7);
                out[(size_t)(b * 4096 + n) * 256 + tn * 16 + l16] = acc[m][r];
            }
    }
}

extern "C" void kernel_launch(void* const* d_in, const int* in_sizes, int n_in,
                              void* d_out, int out_size, void* d_ws, size_t ws_size,
                              hipStream_t stream) {
    const float* x     = (const float*)d_in[0];
    const float* Wqkv  = (const float*)d_in[1];
    const float* bqkv  = (const float*)d_in[2];
    const float* Ek    = (const float*)d_in[3];
    const float* Ev    = (const float*)d_in[4];
    const float* kbank = (const float*)d_in[5];
    const float* vbank = (const float*)d_in[6];
    const float* Wproj = (const float*)d_in[7];
    const float* bproj = (const float*)d_in[8];
    float* outp        = (float*)d_out;
    short* wsp         = (short*)d_ws;
    (void)in_sizes; (void)n_in; (void)out_size; (void)ws_size;

    hipFuncSetAttribute((const void*)eswa_main,
                        hipFuncAttributeMaxDynamicSharedMemorySize, SMEM_BYTES);

    eswa_prep<<<258, 256, 0, stream>>>(Wqkv, Wproj, Ek, Ev, wsp);
    eswa_main<<<1024, 1024, SMEM_BYTES, stream>>>(x, bqkv, kbank, vbank, bproj,
                                                  wsp, outp);
}

// Round 3
// 187.809 us; speedup vs baseline: 1.1110x; 1.1110x over previous
//
#include <hip/hip_runtime.h>
#include <hip/hip_bf16.h>

// B=16, N=4096, C=256, WS=8 -> 1024 windows x 64 tokens; NH=8, HD=32, LK=32, G=16.
// R7: wave-per-head restructure. 512-thread blocks (8 waves), one window/block.
//   Each wave computes its head's QKV (k,v,q kept in registers), Linformer
//   compression via register-fragment transposes (xpose: 8 shfl + 4 cndmask),
//   scores/softmax in registers, P via a 4KB per-wave LDS frag-bounce
//   (linear conflict-free b128 reads), PV, then shared proj.
//   Barriers: 3 (was 6). LDS 64KB (was 128) -> 2 blocks/CU co-resident.
//   Bank K/V fragments and E/W fragments precomputed by eswa_prep.

typedef unsigned int uint;
typedef __attribute__((ext_vector_type(8))) short short8;   // 8 x bf16
typedef __attribute__((ext_vector_type(4))) float f32x4;
typedef __attribute__((ext_vector_type(4))) uint uintx4;

__device__ __forceinline__ float bup(uint hs) {
    return __uint_as_float(hs << 16);
}
__device__ __forceinline__ uint f2b(float f) {   // fp32 -> bf16 bits (RNE, HW cvt)
    __hip_bfloat16 h = __float2bfloat16(f);
    unsigned short u;
    __builtin_memcpy(&u, &h, 2);
    return (uint)u;
}
__device__ __forceinline__ uint f2b2(float a, float b) {  // v_cvt_pk_bf16_f32
    __hip_bfloat162 h = __float22bfloat162_rn(make_float2(a, b));
    uint u;
    __builtin_memcpy(&u, &h, 4);
    return u;
}
__device__ __forceinline__ f32x4 mfma16(short8 a, short8 b, f32x4 c) {
    return __builtin_amdgcn_mfma_f32_16x16x32_bf16(a, b, c, 0, 0, 0);
}
__device__ __forceinline__ int sw256(int r, int c) { return r * 256 + (c ^ ((r & 7) << 3)); }

// C-layout pair (a = m-tile rows 0-15, b = rows 16-31; lane = col l16,
// per-reg rows quad*4+r) -> MFMA operand frag: lane (qf,l16) elem j =
// (row = qf*8+j, col = l16), scaled. 8 shfl + 4 selects, all in-register.
__device__ __forceinline__ short8 xpose(f32x4 a, f32x4 b, float s, int lane) {
    const uint pa0 = f2b2(a[0] * s, a[1] * s), pa1 = f2b2(a[2] * s, a[3] * s);
    const uint pb0 = f2b2(b[0] * s, b[1] * s), pb1 = f2b2(b[2] * s, b[3] * s);
    const int s0 = ((lane >> 4) & 1) * 32 + (lane & 15);   // source quad 2*(qf&1)
    const int s1 = s0 + 16;                                // source quad +1
    const uint w0a = __shfl(pa0, s0), w0b = __shfl(pb0, s0);
    const uint w1a = __shfl(pa1, s0), w1b = __shfl(pb1, s0);
    const uint w2a = __shfl(pa0, s1), w2b = __shfl(pb0, s1);
    const uint w3a = __shfl(pa1, s1), w3b = __shfl(pb1, s1);
    const bool hi = lane >= 32;                            // qf>=2 -> b-tile
    uintx4 u;
    u[0] = hi ? w0b : w0a;
    u[1] = hi ? w1b : w1a;
    u[2] = hi ? w2b : w2a;
    u[3] = hi ? w3b : w3a;
    short8 r;
    __builtin_memcpy(&r, &u, 16);
    return r;
}

// ---- workspace layout (shorts) ----
#define WS_WHQ 0          // Wqkv frags [48 tn][8 tk][64 lane][8] = 196608
#define WS_WHP 196608     // Wproj hi [16 tn][8 tk][64][8] = 65536
#define WS_WLP 262144     // Wproj lo = 65536
#define WS_EKT 327680     // Ek frags [2 tm][2 tk][64][8] = 2048
#define WS_EVT 329728     // Ev frags = 2048
#define WS_KBF 331776     // kbank frags [8 h][64][8] = 4096
#define WS_VBF 335872     // vbank frags [8 h][2 md][64][8] = 8192 (quads>=2 zero)
                          // total 344064 shorts = 688128 B

__global__ void __launch_bounds__(256)
eswa_prep(const float* __restrict__ Wqkv, const float* __restrict__ Wproj,
          const float* __restrict__ Ek, const float* __restrict__ Ev,
          const float* __restrict__ kbank, const float* __restrict__ vbank,
          short* __restrict__ wsp)
{
    const int blk = blockIdx.x, thr = threadIdx.x;
    if (blk < 192) {                      // Wqkv frags: 48 tn x 8 tk x 64 lane, j-half
        const int jh = blk & 1;
        const int g = (blk >> 1) * 256 + thr;
        const int lane = g & 63, tk = (g >> 6) & 7, tn = g >> 9;
        const int quad = lane >> 4, l16 = lane & 15;
        const int c = tn * 16 + l16;
        const int r0 = tk * 32 + quad * 8 + jh * 4;
        const float w0 = Wqkv[(r0 + 0) * 768 + c], w1 = Wqkv[(r0 + 1) * 768 + c];
        const float w2 = Wqkv[(r0 + 2) * 768 + c], w3 = Wqkv[(r0 + 3) * 768 + c];
        *(uint2*)(wsp + WS_WHQ + ((tn * 8 + tk) * 64 + lane) * 8 + jh * 4) =
            make_uint2(f2b2(w0, w1), f2b2(w2, w3));
    } else if (blk < 256) {               // Wproj hi+lo
        const int idx = blk - 192, jh = idx & 1;
        const int g = (idx >> 1) * 256 + thr;
        const int lane = g & 63, tk = (g >> 6) & 7, tn = g >> 9;
        const int quad = lane >> 4, l16 = lane & 15;
        const int c = tn * 16 + l16;
        const int r0 = tk * 32 + quad * 8 + jh * 4;
        float w[4];
        #pragma unroll
        for (int j = 0; j < 4; ++j) w[j] = Wproj[(r0 + j) * 256 + c];
        const uint h01 = f2b2(w[0], w[1]), h23 = f2b2(w[2], w[3]);
        const float l0 = w[0] - bup(h01 & 0xffffu), l1 = w[1] - bup(h01 >> 16);
        const float l2 = w[2] - bup(h23 & 0xffffu), l3 = w[3] - bup(h23 >> 16);
        const int o = ((tn * 8 + tk) * 64 + lane) * 8 + jh * 4;
        *(uint2*)(wsp + WS_WHP + o) = make_uint2(h01, h23);
        *(uint2*)(wsp + WS_WLP + o) = make_uint2(f2b2(l0, l1), f2b2(l2, l3));
    } else if (blk < 258) {               // Ek (256) / Ev (257) frags
        const float* E = (blk == 256) ? Ek : Ev;
        const int base = (blk == 256) ? WS_EKT : WS_EVT;
        const int lane = thr & 63, tk = (thr >> 6) & 1, tm = (thr >> 7) & 1;
        const int quad = lane >> 4, l16 = lane & 15;
        const int lk = tm * 16 + l16;
        uint pk[4];
        #pragma unroll
        for (int jp = 0; jp < 4; ++jp) {
            const int t = tk * 32 + quad * 8 + jp * 2;
            pk[jp] = f2b2(E[t * 32 + lk], E[(t + 1) * 32 + lk]);
        }
        *(uint4*)(wsp + base + ((tm * 2 + tk) * 64 + lane) * 8) =
            make_uint4(pk[0], pk[1], pk[2], pk[3]);
    } else {                              // bank fragments
        // kbank frag [h][lane][8]: elem = kbank[l16][h*32 + quad*8 + j]
        for (int idx = thr; idx < 512; idx += 256) {
            const int hh = idx >> 6, l = idx & 63;
            const int l16 = l & 15, q = l >> 4;
            uint pk[4];
            #pragma unroll
            for (int jp = 0; jp < 4; ++jp)
                pk[jp] = f2b2(kbank[l16 * 256 + hh * 32 + q * 8 + jp * 2],
                              kbank[l16 * 256 + hh * 32 + q * 8 + jp * 2 + 1]);
            *(uint4*)(wsp + WS_KBF + idx * 8) = make_uint4(pk[0], pk[1], pk[2], pk[3]);
        }
        // vbank frag [h][md][lane][8]: quad<2: vbank[quad*8+j][h*32+md*16+l16], else 0
        for (int idx = thr; idx < 1024; idx += 256) {
            const int hh = idx >> 7, md = (idx >> 6) & 1, l = idx & 63;
            const int l16 = l & 15, q = l >> 4;
            uint pk[4] = {0u, 0u, 0u, 0u};
            if (q < 2) {
                #pragma unroll
                for (int jp = 0; jp < 4; ++jp)
                    pk[jp] = f2b2(vbank[(q * 8 + jp * 2) * 256 + hh * 32 + md * 16 + l16],
                                  vbank[(q * 8 + jp * 2 + 1) * 256 + hh * 32 + md * 16 + l16]);
            }
            *(uint4*)(wsp + WS_VBF + idx * 8) = make_uint4(pk[0], pk[1], pk[2], pk[3]);
        }
    }
}

// ---- LDS (bytes), total 65536 ----
// xh   bf16 [64][256] sw256 @ 0     32768  (dead after B2; per-wave 4KB
//                                           P-frag scratch overlays it)
// attn bf16 [64][256] sw256 @ 32768 32768
#define SMEM_BYTES 65536

__global__ void __launch_bounds__(512, 4)
eswa_main(const float* __restrict__ x, const float* __restrict__ bqkv,
          const float* __restrict__ bproj, const short* __restrict__ wsp,
          float* __restrict__ out)
{
    extern __shared__ char smem[];
    short* xh   = (short*)smem;            // [64][256] sw256
    short* attn = (short*)smem + 16384;    // [64][256] sw256

    const int tid  = threadIdx.x;
    const int wave = tid >> 6;             // 0..7 = head
    const int lane = tid & 63;
    const int quad = lane >> 4;
    const int l16  = lane & 15;
    const int h    = wave;

    const int b  = blockIdx.x >> 6;
    const int w  = blockIdx.x & 63;
    const int rw = w >> 3;
    const int cw = w & 7;

    // ================= stage: x -> bf16 LDS [token][256] swizzled ==========
    #pragma unroll
    for (int i = 0; i < 8; ++i) {
        const int vi = tid + 512 * i;             // 0..4095
        const int t  = vi >> 6;
        const int c  = (vi & 63) * 4;
        const int n  = (rw * 8 + (t >> 3)) * 64 + cw * 8 + (t & 7);
        const float4 xv = *(const float4*)(x + (size_t)(b * 4096 + n) * 256 + c);
        *(uint2*)(xh + sw256(t, c)) = make_uint2(f2b2(xv.x, xv.y), f2b2(xv.z, xv.w));
    }
    __syncthreads();   // B1

    const short* WF = wsp + WS_WHQ;

    // ================= phase 1 (per wave = head h) =================
    // ---- k GEMM: C[t][d] (lane=d), acc[nd][mt] -> kfr[nd][kk] = k^T frags
    short8 kfr[2][2], vfr[2][2];
    {
        f32x4 acc[2][4];
        #pragma unroll
        for (int nd = 0; nd < 2; ++nd) {
            const float bk = bqkv[256 + h * 32 + nd * 16 + l16];
            #pragma unroll
            for (int mt = 0; mt < 4; ++mt) acc[nd][mt] = (f32x4){bk, bk, bk, bk};
        }
        #pragma unroll 2
        for (int tk = 0; tk < 8; ++tk) {
            short8 xf[4];
            #pragma unroll
            for (int mt = 0; mt < 4; ++mt)
                xf[mt] = *(const short8*)(xh + sw256(mt * 16 + l16, tk * 32 + quad * 8));
            #pragma unroll
            for (int nd = 0; nd < 2; ++nd) {
                const short8 wf =
                    *(const short8*)(WF + (((16 + h * 2 + nd) * 8 + tk) * 64 + lane) * 8);
                #pragma unroll
                for (int mt = 0; mt < 4; ++mt) acc[nd][mt] = mfma16(xf[mt], wf, acc[nd][mt]);
            }
        }
        #pragma unroll
        for (int nd = 0; nd < 2; ++nd)
            #pragma unroll
            for (int kk = 0; kk < 2; ++kk)
                kfr[nd][kk] = xpose(acc[nd][2 * kk], acc[nd][2 * kk + 1], 1.0f, lane);
    }
    // ---- v GEMM (same structure)
    {
        f32x4 acc[2][4];
        #pragma unroll
        for (int nd = 0; nd < 2; ++nd) {
            const float bv = bqkv[512 + h * 32 + nd * 16 + l16];
            #pragma unroll
            for (int mt = 0; mt < 4; ++mt) acc[nd][mt] = (f32x4){bv, bv, bv, bv};
        }
        #pragma unroll 2
        for (int tk = 0; tk < 8; ++tk) {
            short8 xf[4];
            #pragma unroll
            for (int mt = 0; mt < 4; ++mt)
                xf[mt] = *(const short8*)(xh + sw256(mt * 16 + l16, tk * 32 + quad * 8));
            #pragma unroll
            for (int nd = 0; nd < 2; ++nd) {
                const short8 wf =
                    *(const short8*)(WF + (((32 + h * 2 + nd) * 8 + tk) * 64 + lane) * 8);
                #pragma unroll
                for (int mt = 0; mt < 4; ++mt) acc[nd][mt] = mfma16(xf[mt], wf, acc[nd][mt]);
            }
        }
        #pragma unroll
        for (int nd = 0; nd < 2; ++nd)
            #pragma unroll
            for (int kk = 0; kk < 2; ++kk)
                vfr[nd][kk] = xpose(acc[nd][2 * kk], acc[nd][2 * kk + 1], 1.0f, lane);
    }
    // ---- Linformer compression, all in registers
    short8 kcf[2], vcf[2];
    {
        short8 ekf[2][2], evf[2][2];
        #pragma unroll
        for (int tm = 0; tm < 2; ++tm)
            #pragma unroll
            for (int kk = 0; kk < 2; ++kk) {
                ekf[tm][kk] = *(const short8*)(wsp + WS_EKT + ((tm * 2 + kk) * 64 + lane) * 8);
                evf[tm][kk] = *(const short8*)(wsp + WS_EVT + ((tm * 2 + kk) * 64 + lane) * 8);
            }
        // kcT[d][lk] = sum_t k[t][d] * Ek[t][lk]; C lane = lk
        f32x4 ck[2][2];   // [md][nlk]
        #pragma unroll
        for (int md = 0; md < 2; ++md)
            #pragma unroll
            for (int nl = 0; nl < 2; ++nl) ck[md][nl] = (f32x4){0, 0, 0, 0};
        #pragma unroll
        for (int kk = 0; kk < 2; ++kk)
            #pragma unroll
            for (int md = 0; md < 2; ++md)
                #pragma unroll
                for (int nl = 0; nl < 2; ++nl)
                    ck[md][nl] = mfma16(kfr[md][kk], ekf[nl][kk], ck[md][nl]);
        #pragma unroll
        for (int nl = 0; nl < 2; ++nl)
            kcf[nl] = xpose(ck[0][nl], ck[1][nl], 1.0f, lane);   // [key=lk][d] frags
        // vc[lk][d] = sum_t Ev[t][lk] * v[t][d]; C lane = d
        f32x4 cv[2][2];   // [mlk][nd]
        #pragma unroll
        for (int ml = 0; ml < 2; ++ml)
            #pragma unroll
            for (int nd = 0; nd < 2; ++nd) cv[ml][nd] = (f32x4){0, 0, 0, 0};
        #pragma unroll
        for (int kk = 0; kk < 2; ++kk)
            #pragma unroll
            for (int ml = 0; ml < 2; ++ml)
                #pragma unroll
                for (int nd = 0; nd < 2; ++nd)
                    cv[ml][nd] = mfma16(evf[ml][kk], vfr[nd][kk], cv[ml][nd]);
        #pragma unroll
        for (int nd = 0; nd < 2; ++nd)
            vcf[nd] = xpose(cv[0][nd], cv[1][nd], 1.0f, lane);   // [d][key=lk] frags
    }
    const short8 kbf = *(const short8*)(wsp + WS_KBF + (h * 64 + lane) * 8);
    short8 vbf[2];
    #pragma unroll
    for (int md = 0; md < 2; ++md)
        vbf[md] = *(const short8*)(wsp + WS_VBF + ((h * 2 + md) * 64 + lane) * 8);

    // ---- q GEMM transposed: C[d][t] (lane=t), acc[md][nt] -> qfr[nt] A-frags
    short8 qfr[4];
    {
        f32x4 acc[2][4];
        #pragma unroll
        for (int md = 0; md < 2; ++md) {
            const float4 bq = *(const float4*)(bqkv + h * 32 + md * 16 + quad * 4);
            #pragma unroll
            for (int nt = 0; nt < 4; ++nt) acc[md][nt] = (f32x4){bq.x, bq.y, bq.z, bq.w};
        }
        #pragma unroll 2
        for (int tk = 0; tk < 8; ++tk) {
            short8 xf[4];
            #pragma unroll
            for (int nt = 0; nt < 4; ++nt)
                xf[nt] = *(const short8*)(xh + sw256(nt * 16 + l16, tk * 32 + quad * 8));
            #pragma unroll
            for (int md = 0; md < 2; ++md) {
                const short8 wf =
                    *(const short8*)(WF + (((h * 2 + md) * 8 + tk) * 64 + lane) * 8);
                #pragma unroll
                for (int nt = 0; nt < 4; ++nt) acc[md][nt] = mfma16(wf, xf[nt], acc[md][nt]);
            }
        }
        #pragma unroll
        for (int nt = 0; nt < 4; ++nt)
            qfr[nt] = xpose(acc[0][nt], acc[1][nt], 0.17677669529663687f, lane);
    }
    __syncthreads();   // B2: xh dead -> per-wave P scratch

    // ================= phase 2: scores/softmax/PV (wave-local) =============
    short* scr = (short*)smem + wave * 2048;   // 4KB: P frags [mt*2+kk][64][8]
    // zero the never-written key 48-63 slots (kk=1, lanes>=32) once
    if (lane >= 32) {
        *(uint4*)(scr + (1 * 64 + lane) * 8) = make_uint4(0, 0, 0, 0);
        *(uint4*)(scr + (3 * 64 + lane) * 8) = make_uint4(0, 0, 0, 0);
    }

    #pragma unroll
    for (int th = 0; th < 2; ++th) {
        // scores C[t][key] (lane=key), 48 keys = 3 n-tiles
        f32x4 sc[2][3];
        #pragma unroll
        for (int mt = 0; mt < 2; ++mt) {
            const short8 qa = qfr[th * 2 + mt];
            sc[mt][0] = mfma16(qa, kcf[0], (f32x4){0, 0, 0, 0});
            sc[mt][1] = mfma16(qa, kcf[1], (f32x4){0, 0, 0, 0});
            sc[mt][2] = mfma16(qa, kbf,    (f32x4){0, 0, 0, 0});
        }
        // softmax over keys: 3 in-thread + shfl over l16
        float inv[2][4];
        #pragma unroll
        for (int mt = 0; mt < 2; ++mt) {
            #pragma unroll
            for (int r = 0; r < 4; ++r) {
                float mm = fmaxf(fmaxf(sc[mt][0][r], sc[mt][1][r]), sc[mt][2][r]);
                mm = fmaxf(mm, __shfl_xor(mm, 1));
                mm = fmaxf(mm, __shfl_xor(mm, 2));
                mm = fmaxf(mm, __shfl_xor(mm, 4));
                mm = fmaxf(mm, __shfl_xor(mm, 8));
                const float e0 = __expf(sc[mt][0][r] - mm);
                const float e1 = __expf(sc[mt][1][r] - mm);
                const float e2 = __expf(sc[mt][2][r] - mm);
                sc[mt][0][r] = e0; sc[mt][1][r] = e1; sc[mt][2][r] = e2;
                float su = e0 + e1 + e2;
                su += __shfl_xor(su, 1);
                su += __shfl_xor(su, 2);
                su += __shfl_xor(su, 4);
                su += __shfl_xor(su, 8);
                inv[mt][r] = 1.0f / su;
            }
        }
        // P frag-bounce: scatter P[t][key] into operand-frag slots
        #pragma unroll
        for (int mt = 0; mt < 2; ++mt)
            #pragma unroll
            for (int nk = 0; nk < 3; ++nk) {
                const int qt = (nk * 2 + (l16 >> 3)) & 3;
                const int base = (mt * 2 + (nk >> 1)) * 64 + qt * 16 + quad * 4;
                #pragma unroll
                for (int r = 0; r < 4; ++r)
                    scr[(base + r) * 8 + (l16 & 7)] =
                        (short)f2b(sc[mt][nk][r] * inv[mt][r]);
            }
        asm volatile("s_waitcnt lgkmcnt(0)" ::: "memory");
        __builtin_amdgcn_sched_barrier(0);
        short8 pa[2][2];
        #pragma unroll
        for (int mt = 0; mt < 2; ++mt)
            #pragma unroll
            for (int kk = 0; kk < 2; ++kk)
                pa[mt][kk] = *(const short8*)(scr + ((mt * 2 + kk) * 64 + lane) * 8);
        // PV: C[d][t] (lane=t) = vfull[key][d]^T x P[t][key]
        #pragma unroll
        for (int mt = 0; mt < 2; ++mt)
            #pragma unroll
            for (int md = 0; md < 2; ++md) {
                f32x4 o = mfma16(vcf[md], pa[mt][0], (f32x4){0, 0, 0, 0});
                o = mfma16(vbf[md], pa[mt][1], o);
                *(uint2*)(attn + sw256((th * 2 + mt) * 16 + l16,
                                       h * 32 + md * 16 + quad * 4)) =
                    make_uint2(f2b2(o[0], o[1]), f2b2(o[2], o[3]));
            }
    }
    __syncthreads();   // B3: attn ready

    // ================= phase 3: output projection =================
    // wave handles tn = 2*wave, 2*wave+1; W hi+lo.
    {
        const short* Whp = wsp + WS_WHP;
        const short* Wlp = wsp + WS_WLP;
        f32x4 acc[2][4];
        #pragma unroll
        for (int p = 0; p < 2; ++p) {
            const float bi = bproj[(wave * 2 + p) * 16 + l16];
            #pragma unroll
            for (int m = 0; m < 4; ++m) acc[p][m] = (f32x4){bi, bi, bi, bi};
        }
        #pragma unroll 2
        for (int tk = 0; tk < 8; ++tk) {
            short8 aA[4];
            #pragma unroll
            for (int m = 0; m < 4; ++m)
                aA[m] = *(const short8*)(attn + sw256(m * 16 + l16, tk * 32 + quad * 8));
            #pragma unroll
            for (int p = 0; p < 2; ++p) {
                const int bo = (((wave * 2 + p) * 8 + tk) * 64 + lane) * 8;
                const short8 bh = *(const short8*)(Whp + bo);
                const short8 bl = *(const short8*)(Wlp + bo);
                #pragma unroll
                for (int m = 0; m < 4; ++m) {
                    acc[p][m] = mfma16(aA[m], bh, acc[p][m]);
                    acc[p][m] = mfma16(aA[m], bl, acc[p][m]);
                }
            }
        }
        #pragma unroll
        for (int p = 0; p < 2; ++p)
            #pragma unroll
            for (int m = 0; m < 4; ++m)
                #pragma unroll
                for (int r = 0; r < 4; ++r) {
                    const int t = m * 16 + quad * 4 + r;
                    const int n = (rw * 8 + (t >> 3)) * 64 + cw * 8 + (t & 7);
                    out[(size_t)(b * 4096 + n) * 256 + (wave * 2 + p) * 16 + l16] =
                        acc[p][m][r];
                }
    }
}

extern "C" void kernel_launch(void* const* d_in, const int* in_sizes, int n_in,
                              void* d_out, int out_size, void* d_ws, size_t ws_size,
                              hipStream_t stream) {
    const float* x     = (const float*)d_in[0];
    const float* Wqkv  = (const float*)d_in[1];
    const float* bqkv  = (const float*)d_in[2];
    const float* Ek    = (const float*)d_in[3];
    const float* Ev    = (const float*)d_in[4];
    const float* kbank = (const float*)d_in[5];
    const float* vbank = (const float*)d_in[6];
    const float* Wproj = (const float*)d_in[7];
    const float* bproj = (const float*)d_in[8];
    float* outp        = (float*)d_out;
    short* wsp         = (short*)d_ws;
    (void)in_sizes; (void)n_in; (void)out_size; (void)ws_size;

    (void)hipFuncSetAttribute((const void*)eswa_main,
                              hipFuncAttributeMaxDynamicSharedMemorySize, SMEM_BYTES);

    eswa_prep<<<259, 256, 0, stream>>>(Wqkv, Wproj, Ek, Ev, kbank, vbank, wsp);
    eswa_main<<<1024, 512, SMEM_BYTES, stream>>>(x, bqkv, bproj, wsp, outp);
}